// Round 7
// baseline (121.360 us; speedup 1.0000x reference)
//
#include <hip/hip_runtime.h>
#include <math.h>

// B=1024, D=128, H=128
#define Bn 1024
#define Dn 128
#define Hn 128

// 256 blocks x 1024 threads (16 waves/CU, 1 block/CU). Block owns 4 i-rows.
// Phase 1: j in 8 tiles of 128 rows, double-buffered LDS staging (64 KB each).
//   Stage tile k+1 (coalesced 1KB/instr global_load_dwordx4, issued before the
//   barrier) while computing tile k from LDS via ds_read_b128 with immediate
//   offsets. Thread (q = t>>5 in [0,32) -> tile rows 4q..4q+3, c4 = t&31 ->
//   cols 4c4..4c4+3): 128 arith VALU per tile, 1 barrier per tile (8 total).
// LDS aliasing (single 139792 B block):
//   [0,64K)=buf0  [64K,128K)=buf1  red[32][4][128] aliases buf0 AFTER the last
//   buf0 read (tile 6 reads complete before barrier_7; tile 7 reads buf1 only).
//   Epilogue arrays live at [128K,136.5K) - never overlap the buffers.
// Phase 2: reduce 32 q-groups -> dms. Phases 3-5: verified epilogue.
__global__ __launch_bounds__(1024) void fused_resd1(
    const float* __restrict__ x,
    const float* __restrict__ Wd, const float* __restrict__ bd,
    const float* __restrict__ Wt, const float* __restrict__ bt,
    const float* __restrict__ Wa, const float* __restrict__ ba,
    const float* __restrict__ Wr, const float* __restrict__ br,
    const float* __restrict__ gamma, const float* __restrict__ beta,
    float* __restrict__ out) {
  const int t = threadIdx.x;
  const int c4 = t & 31;   // float4 column: cols 4c4..4c4+3
  const int q = t >> 5;    // tile-row group in [0,32)
  const int i0 = blockIdx.x << 2;

  __shared__ __align__(16) unsigned char smem_raw[139792];
  float* const sbuf0 = (float*)smem_raw;             // 64 KB j-tile buffer 0
  float* const sbuf1 = (float*)(smem_raw + 65536);   // 64 KB j-tile buffer 1
  float* const red   = (float*)smem_raw;             // [32][4][128] aliases buf0
  float* const xs    = (float*)(smem_raw + 131072);  // 4*128
  float* const dms   = xs + 512;                     // 4*128
  float* const ms    = dms + 512;                    // 4*128
  float* const ys    = ms + 512;                     // 4*128
  float* const wt_s  = ys + 512;                     // 128
  float* const tau_s = wt_s + 128;                   // 4 (stores 1/tau)

  // ---- Phase 1 ----
  float4 xi[4];
#pragma unroll
  for (int r = 0; r < 4; ++r)
    xi[r] = *(const float4*)(x + (size_t)(i0 + r) * Dn + c4 * 4);

  float4 acc[4];
#pragma unroll
  for (int r = 0; r < 4; ++r) acc[r] = make_float4(0.f, 0.f, 0.f, 0.f);

  const float4* gx = (const float4*)x;  // 32768 float4s; tile k = [k*4096, +4096)

  {  // prime tile 0: 64 KB staged by 1024 threads, 4 float4 each
    float4 s0[4];
#pragma unroll
    for (int u = 0; u < 4; ++u) s0[u] = gx[u * 1024 + t];
#pragma unroll
    for (int u = 0; u < 4; ++u) *(float4*)(sbuf0 + (u * 1024 + t) * 4) = s0[u];
  }

#pragma unroll 1
  for (int k = 0; k < 8; ++k) {
    float4 nx[4];
    if (k < 7) {  // issue next tile's loads; they fly across the barrier
#pragma unroll
      for (int u = 0; u < 4; ++u)
        nx[u] = gx[(size_t)(k + 1) * 4096 + u * 1024 + t];
    }
    __syncthreads();  // buf[k&1] fully staged; buf[(k+1)&1] reads all done
    const float* tbp = ((k & 1) ? sbuf1 : sbuf0) + (q * 4) * Dn + c4 * 4;
#pragma unroll
    for (int u = 0; u < 4; ++u) {
      const float4 xj = *(const float4*)(tbp + u * Dn);  // imm-offset b128
#pragma unroll
      for (int r = 0; r < 4; ++r) {
        acc[r].x += fabsf(xi[r].x - xj.x);
        acc[r].y += fabsf(xi[r].y - xj.y);
        acc[r].z += fabsf(xi[r].z - xj.z);
        acc[r].w += fabsf(xi[r].w - xj.w);
      }
    }
    if (k < 7) {
      float* nb = ((k + 1) & 1) ? sbuf1 : sbuf0;
#pragma unroll
      for (int u = 0; u < 4; ++u) *(float4*)(nb + (u * 1024 + t) * 4) = nx[u];
    }
  }

  // red aliases buf0: all buf0 reads (last at tile 6) completed before
  // barrier_7; tile-7 compute reads buf1 only -> safe to write now.
#pragma unroll
  for (int r = 0; r < 4; ++r)
    *(float4*)(red + q * 512 + r * Dn + c4 * 4) = acc[r];
  __syncthreads();

  // ---- Phase 2: reduce 32 q-groups; stage xs, wt_s ----
  if (t < 512) {
    const int r = t >> 7, d = t & 127;
    float s = 0.f;
#pragma unroll
    for (int qq = 0; qq < 32; ++qq) s += red[qq * 512 + r * Dn + d];
    dms[r * Dn + d] = s * (1.0f / 1024.0f);
    xs[r * Dn + d] = x[(size_t)(i0 + r) * Dn + d];
  } else if (t < 640) {
    wt_s[t - 512] = Wt[t - 512];
  }
  __syncthreads();

  // ---- Phase 3: tau (one wave per row, t<256) ----
  if (t < 256) {
    const int r = t >> 6, p = t & 63;
    float partial = xs[r * Dn + p] * wt_s[p] + xs[r * Dn + p + 64] * wt_s[p + 64];
#pragma unroll
    for (int off = 32; off; off >>= 1) partial += __shfl_xor(partial, off, 64);
    if (p == 0) {
      const float z = partial + bt[0];
      const float sp = fmaxf(z, 0.f) + log1pf(expf(-fabsf(z)));  // softplus
      tau_s[r] = 1.0f / (fmaxf(sp, 0.01f) + 1.0f);
    }
  }
  __syncthreads();

  // ---- Phase 4a: m = (Wd . dm + bd) / tau (t<256) ----
  if (t < 256) {
    const int h = t & 127;
    const int g4 = t >> 7;
    const int r0 = 2 * g4, r1 = 2 * g4 + 1;
    float m0 = bd[h], m1 = m0;
    const float4* w = (const float4*)(Wd + (size_t)h * Dn);
#pragma unroll 4
    for (int k4 = 0; k4 < Dn / 4; ++k4) {
      const float4 wv = w[k4];
      const int k = k4 * 4;
      m0 += wv.x * dms[r0 * Dn + k] + wv.y * dms[r0 * Dn + k + 1] +
            wv.z * dms[r0 * Dn + k + 2] + wv.w * dms[r0 * Dn + k + 3];
      m1 += wv.x * dms[r1 * Dn + k] + wv.y * dms[r1 * Dn + k + 1] +
            wv.z * dms[r1 * Dn + k + 2] + wv.w * dms[r1 * Dn + k + 3];
    }
    ms[r0 * Dn + h] = m0 * tau_s[r0];
    ms[r1 * Dn + h] = m1 * tau_s[r1];
  }
  __syncthreads();

  // ---- Phase 4b: y = relu(Wa . m + ba) + Wr . x + br (t<256) ----
  if (t < 256) {
    const int h = t & 127;
    const int g4 = t >> 7;
    const int r0 = 2 * g4, r1 = 2 * g4 + 1;
    float q0 = ba[h], q1 = q0, c0 = br[h], c1 = c0;
    const float4* wa = (const float4*)(Wa + (size_t)h * Dn);
    const float4* wr = (const float4*)(Wr + (size_t)h * Dn);
#pragma unroll 4
    for (int k4 = 0; k4 < Dn / 4; ++k4) {
      const float4 av = wa[k4];
      const float4 rv = wr[k4];
      const int k = k4 * 4;
      q0 += av.x * ms[r0 * Dn + k] + av.y * ms[r0 * Dn + k + 1] +
            av.z * ms[r0 * Dn + k + 2] + av.w * ms[r0 * Dn + k + 3];
      q1 += av.x * ms[r1 * Dn + k] + av.y * ms[r1 * Dn + k + 1] +
            av.z * ms[r1 * Dn + k + 2] + av.w * ms[r1 * Dn + k + 3];
      c0 += rv.x * xs[r0 * Dn + k] + rv.y * xs[r0 * Dn + k + 1] +
            rv.z * xs[r0 * Dn + k + 2] + rv.w * xs[r0 * Dn + k + 3];
      c1 += rv.x * xs[r1 * Dn + k] + rv.y * xs[r1 * Dn + k + 1] +
            rv.z * xs[r1 * Dn + k + 2] + rv.w * xs[r1 * Dn + k + 3];
    }
    ys[r0 * Dn + h] = fmaxf(q0, 0.f) + c0;
    ys[r1 * Dn + h] = fmaxf(q1, 0.f) + c1;
  }
  __syncthreads();

  // ---- Phase 5: LayerNorm (one wave per row, t<256) ----
  if (t < 256) {
    const int r = t >> 6, p = t & 63;
    const float v0 = ys[r * Dn + p], v1 = ys[r * Dn + p + 64];
    float s = v0 + v1;
    float qq = v0 * v0 + v1 * v1;
#pragma unroll
    for (int off = 32; off; off >>= 1) {
      s += __shfl_xor(s, off, 64);
      qq += __shfl_xor(qq, off, 64);
    }
    const float mu = s * (1.0f / 128.0f);
    const float var = qq * (1.0f / 128.0f) - mu * mu;
    const float rs = rsqrtf(var + 1e-5f);
    float* o = out + (size_t)(i0 + r) * Hn;
    o[p]      = (v0 - mu) * rs * gamma[p]      + beta[p];
    o[p + 64] = (v1 - mu) * rs * gamma[p + 64] + beta[p + 64];
  }
}

extern "C" void kernel_launch(void* const* d_in, const int* in_sizes, int n_in,
                              void* d_out, int out_size, void* d_ws, size_t ws_size,
                              hipStream_t stream) {
  const float* x     = (const float*)d_in[0];
  const float* Wd    = (const float*)d_in[1];
  const float* bd    = (const float*)d_in[2];
  const float* Wt    = (const float*)d_in[3];
  const float* bt    = (const float*)d_in[4];
  const float* Wa    = (const float*)d_in[5];
  const float* ba    = (const float*)d_in[6];
  const float* Wr    = (const float*)d_in[7];
  const float* br    = (const float*)d_in[8];
  const float* gamma = (const float*)d_in[9];
  const float* beta  = (const float*)d_in[10];
  float* out = (float*)d_out;

  fused_resd1<<<Bn / 4, 1024, 0, stream>>>(x, Wd, bd, Wt, bt, Wa, ba, Wr, br,
                                           gamma, beta, out);
  (void)in_sizes; (void)n_in; (void)out_size; (void)d_ws; (void)ws_size;
}

// Round 8
// 102.797 us; speedup vs baseline: 1.1806x; 1.1806x over previous
//
#include <hip/hip_runtime.h>
#include <math.h>

// B=1024, D=128, H=128
#define Bn 1024
#define Dn 128
#define Hn 128

// Async global->LDS staging, 16B width (no VGPR roundtrip, no spills).
// Per-lane global addr; wave-uniform LDS base + lane*16 (HW-added).
typedef __attribute__((address_space(3))) void lds_void;
typedef const __attribute__((address_space(1))) void gm_void;
__device__ __forceinline__ void stage16(const void* g, void* l) {
  __builtin_amdgcn_global_load_lds((gm_void*)g, (lds_void*)l, 16, 0, 0);
}

// 256 blocks x 1024 threads (16 waves/CU, 1 block/CU). Block owns 4 i-rows.
// Phase 1: j in 8 tiles of 128 rows, double-buffered LDS staging via
//   global_load_lds_dwordx4 (4 instr/wave/tile, 1KB each). Barrier at loop
//   top: tile k staged AND tile k-1 readers done -> safe to issue k+1 into
//   the buffer tile k-1 used. Compute tile k: thread (q = t>>5 -> tile rows
//   4q..4q+3, c4 = t&31 -> cols 4c4..4c4+3), ds_read_b128, 128 arith VALU.
// LDS aliasing (139792 B): [0,64K)=buf0 [64K,128K)=buf1; red[32][4][128]
//   aliases buf0 (last buf0 read = tile 6, done before barrier_7; tile 7
//   reads buf1 only). Epilogue arrays at [128K,136.5K).
// Phase 2: reduce 32 q-groups -> dms. Phases 3-5: verified epilogue.
__global__ __launch_bounds__(1024) void fused_resd1(
    const float* __restrict__ x,
    const float* __restrict__ Wd, const float* __restrict__ bd,
    const float* __restrict__ Wt, const float* __restrict__ bt,
    const float* __restrict__ Wa, const float* __restrict__ ba,
    const float* __restrict__ Wr, const float* __restrict__ br,
    const float* __restrict__ gamma, const float* __restrict__ beta,
    float* __restrict__ out) {
  const int t = threadIdx.x;
  const int c4 = t & 31;   // float4 column: cols 4c4..4c4+3
  const int q = t >> 5;    // tile-row group in [0,32)
  const int lane = t & 63;
  const int wave = t >> 6; // wave-uniform
  const int i0 = blockIdx.x << 2;

  __shared__ __align__(16) unsigned char smem_raw[139792];
  float* const sbuf0 = (float*)smem_raw;             // 64 KB j-tile buffer 0
  float* const sbuf1 = (float*)(smem_raw + 65536);   // 64 KB j-tile buffer 1
  float* const red   = (float*)smem_raw;             // [32][4][128] aliases buf0
  float* const xs    = (float*)(smem_raw + 131072);  // 4*128
  float* const dms   = xs + 512;                     // 4*128
  float* const ms    = dms + 512;                    // 4*128
  float* const ys    = ms + 512;                     // 4*128
  float* const wt_s  = ys + 512;                     // 128
  float* const tau_s = wt_s + 128;                   // 4 (stores 1/tau)

  // ---- Phase 1 ----
  float4 xi[4];
#pragma unroll
  for (int r = 0; r < 4; ++r)
    xi[r] = *(const float4*)(x + (size_t)(i0 + r) * Dn + c4 * 4);

  float4 acc[4];
#pragma unroll
  for (int r = 0; r < 4; ++r) acc[r] = make_float4(0.f, 0.f, 0.f, 0.f);

  // tile k = float4s [k*4096, +4096); wave stages chunks u: f4 idx
  // wave*256 + u*64 + lane; LDS base (floats) wave*1024 + u*256 (+lane*4 by HW)
  const float4* gt = (const float4*)x + wave * 256 + lane;
  const int lb = wave * 1024;  // float offset of this wave's staging region

  // prime tile 0 -> buf0
#pragma unroll
  for (int u = 0; u < 4; ++u)
    stage16(gt + u * 64, sbuf0 + lb + u * 256);

#pragma unroll
  for (int k = 0; k < 8; ++k) {
    __syncthreads();  // tile k staged (vmcnt drained); tile k-1 readers done
    if (k < 7) {      // issue tile k+1 into the buffer tile k-1 vacated
      float* nb = ((k + 1) & 1) ? sbuf1 : sbuf0;
#pragma unroll
      for (int u = 0; u < 4; ++u)
        stage16(gt + (k + 1) * 4096 + u * 64, nb + lb + u * 256);
    }
    const float* tbp = ((k & 1) ? sbuf1 : sbuf0) + (q * 4) * Dn + c4 * 4;
#pragma unroll
    for (int u = 0; u < 4; ++u) {
      const float4 xj = *(const float4*)(tbp + u * Dn);  // imm-offset b128
#pragma unroll
      for (int r = 0; r < 4; ++r) {
        acc[r].x += fabsf(xi[r].x - xj.x);
        acc[r].y += fabsf(xi[r].y - xj.y);
        acc[r].z += fabsf(xi[r].z - xj.z);
        acc[r].w += fabsf(xi[r].w - xj.w);
      }
    }
  }

  // red aliases buf0: last buf0 reads (tile 6) completed before barrier_7;
  // tile-7 compute reads buf1 only -> each wave may write red now.
#pragma unroll
  for (int r = 0; r < 4; ++r)
    *(float4*)(red + q * 512 + r * Dn + c4 * 4) = acc[r];
  __syncthreads();

  // ---- Phase 2: reduce 32 q-groups; stage xs, wt_s ----
  if (t < 512) {
    const int r = t >> 7, d = t & 127;
    float s = 0.f;
#pragma unroll
    for (int qq = 0; qq < 32; ++qq) s += red[qq * 512 + r * Dn + d];
    dms[r * Dn + d] = s * (1.0f / 1024.0f);
    xs[r * Dn + d] = x[(size_t)(i0 + r) * Dn + d];
  } else if (t < 640) {
    wt_s[t - 512] = Wt[t - 512];
  }
  __syncthreads();

  // ---- Phase 3: tau (one wave per row, t<256) ----
  if (t < 256) {
    const int r = t >> 6, p = t & 63;
    float partial = xs[r * Dn + p] * wt_s[p] + xs[r * Dn + p + 64] * wt_s[p + 64];
#pragma unroll
    for (int off = 32; off; off >>= 1) partial += __shfl_xor(partial, off, 64);
    if (p == 0) {
      const float z = partial + bt[0];
      const float sp = fmaxf(z, 0.f) + log1pf(expf(-fabsf(z)));  // softplus
      tau_s[r] = 1.0f / (fmaxf(sp, 0.01f) + 1.0f);
    }
  }
  __syncthreads();

  // ---- Phase 4a: m = (Wd . dm + bd) / tau (t<256) ----
  if (t < 256) {
    const int h = t & 127;
    const int g4 = t >> 7;
    const int r0 = 2 * g4, r1 = 2 * g4 + 1;
    float m0 = bd[h], m1 = m0;
    const float4* w = (const float4*)(Wd + (size_t)h * Dn);
#pragma unroll 4
    for (int k4 = 0; k4 < Dn / 4; ++k4) {
      const float4 wv = w[k4];
      const int k = k4 * 4;
      m0 += wv.x * dms[r0 * Dn + k] + wv.y * dms[r0 * Dn + k + 1] +
            wv.z * dms[r0 * Dn + k + 2] + wv.w * dms[r0 * Dn + k + 3];
      m1 += wv.x * dms[r1 * Dn + k] + wv.y * dms[r1 * Dn + k + 1] +
            wv.z * dms[r1 * Dn + k + 2] + wv.w * dms[r1 * Dn + k + 3];
    }
    ms[r0 * Dn + h] = m0 * tau_s[r0];
    ms[r1 * Dn + h] = m1 * tau_s[r1];
  }
  __syncthreads();

  // ---- Phase 4b: y = relu(Wa . m + ba) + Wr . x + br (t<256) ----
  if (t < 256) {
    const int h = t & 127;
    const int g4 = t >> 7;
    const int r0 = 2 * g4, r1 = 2 * g4 + 1;
    float q0 = ba[h], q1 = q0, c0 = br[h], c1 = c0;
    const float4* wa = (const float4*)(Wa + (size_t)h * Dn);
    const float4* wr = (const float4*)(Wr + (size_t)h * Dn);
#pragma unroll 4
    for (int k4 = 0; k4 < Dn / 4; ++k4) {
      const float4 av = wa[k4];
      const float4 rv = wr[k4];
      const int k = k4 * 4;
      q0 += av.x * ms[r0 * Dn + k] + av.y * ms[r0 * Dn + k + 1] +
            av.z * ms[r0 * Dn + k + 2] + av.w * ms[r0 * Dn + k + 3];
      q1 += av.x * ms[r1 * Dn + k] + av.y * ms[r1 * Dn + k + 1] +
            av.z * ms[r1 * Dn + k + 2] + av.w * ms[r1 * Dn + k + 3];
      c0 += rv.x * xs[r0 * Dn + k] + rv.y * xs[r0 * Dn + k + 1] +
            rv.z * xs[r0 * Dn + k + 2] + rv.w * xs[r0 * Dn + k + 3];
      c1 += rv.x * xs[r1 * Dn + k] + rv.y * xs[r1 * Dn + k + 1] +
            rv.z * xs[r1 * Dn + k + 2] + rv.w * xs[r1 * Dn + k + 3];
    }
    ys[r0 * Dn + h] = fmaxf(q0, 0.f) + c0;
    ys[r1 * Dn + h] = fmaxf(q1, 0.f) + c1;
  }
  __syncthreads();

  // ---- Phase 5: LayerNorm (one wave per row, t<256) ----
  if (t < 256) {
    const int r = t >> 6, p = t & 63;
    const float v0 = ys[r * Dn + p], v1 = ys[r * Dn + p + 64];
    float s = v0 + v1;
    float qq = v0 * v0 + v1 * v1;
#pragma unroll
    for (int off = 32; off; off >>= 1) {
      s += __shfl_xor(s, off, 64);
      qq += __shfl_xor(qq, off, 64);
    }
    const float mu = s * (1.0f / 128.0f);
    const float var = qq * (1.0f / 128.0f) - mu * mu;
    const float rs = rsqrtf(var + 1e-5f);
    float* o = out + (size_t)(i0 + r) * Hn;
    o[p]      = (v0 - mu) * rs * gamma[p]      + beta[p];
    o[p + 64] = (v1 - mu) * rs * gamma[p + 64] + beta[p + 64];
  }
}

extern "C" void kernel_launch(void* const* d_in, const int* in_sizes, int n_in,
                              void* d_out, int out_size, void* d_ws, size_t ws_size,
                              hipStream_t stream) {
  const float* x     = (const float*)d_in[0];
  const float* Wd    = (const float*)d_in[1];
  const float* bd    = (const float*)d_in[2];
  const float* Wt    = (const float*)d_in[3];
  const float* bt    = (const float*)d_in[4];
  const float* Wa    = (const float*)d_in[5];
  const float* ba    = (const float*)d_in[6];
  const float* Wr    = (const float*)d_in[7];
  const float* br    = (const float*)d_in[8];
  const float* gamma = (const float*)d_in[9];
  const float* beta  = (const float*)d_in[10];
  float* out = (float*)d_out;

  fused_resd1<<<Bn / 4, 1024, 0, stream>>>(x, Wd, bd, Wt, bt, Wa, ba, Wr, br,
                                           gamma, beta, out);
  (void)in_sizes; (void)n_in; (void)out_size; (void)d_ws; (void)ws_size;
}

// Round 9
// 97.441 us; speedup vs baseline: 1.2455x; 1.0550x over previous
//
#include <hip/hip_runtime.h>
#include <math.h>

// B=1024, D=128, H=128
#define Bn 1024
#define Dn 128
#define Hn 128

// 256 blocks x 1024 threads (16 waves/CU, 1 block/CU). Block owns 4 i-rows.
// Phase 1: j in 16 tiles of 64 rows, double-buffered LDS staging with a
//   ONE-ITERATION PHASE SHIFT so no barrier ever drains a just-issued load:
//     iter k: [write tile k+1 regs->LDS] [issue tile k+2 loads] [compute k]
//             [barrier]  <- vmcnt drain covered by compute-k (~700 cyc)
//   Thread (q = t>>6 wave id -> tile rows 4q..4q+3, c2 = t&63 -> cols
//   2c2,2c2+1): 64 arith VALU per tile via ds_read_b64 (2-way aliasing, free).
// Phase 2: LDS tree-reduce 16 wave-partials -> dms.
// Phases 3-5: tau, matvecs, LayerNorm (verified epilogue, t<256).
__global__ __launch_bounds__(1024) void fused_resd1(
    const float* __restrict__ x,
    const float* __restrict__ Wd, const float* __restrict__ bd,
    const float* __restrict__ Wt, const float* __restrict__ bt,
    const float* __restrict__ Wa, const float* __restrict__ ba,
    const float* __restrict__ Wr, const float* __restrict__ br,
    const float* __restrict__ gamma, const float* __restrict__ beta,
    float* __restrict__ out) {
  const int t = threadIdx.x;
  const int c2 = t & 63;     // col pair: cols 2c2, 2c2+1
  const int lane = t & 63;
  const int wave = t >> 6;   // in [0,16): tile-row group AND staging slot
  const int i0 = blockIdx.x << 2;

  __shared__ float bufA[64 * Dn];   // 32 KB j-tile buffer (even tiles)
  __shared__ float bufB[64 * Dn];   // 32 KB j-tile buffer (odd tiles)
  __shared__ float red[16][4][Dn];  // 32 KB per-wave partial column sums
  __shared__ float xs[4][Dn];
  __shared__ float dms[4][Dn];
  __shared__ float ms[4][Hn];
  __shared__ float ys[4][Hn];
  __shared__ float wt_s[Dn];
  __shared__ float tau_s[4];        // 1/tau

  // ---- Phase 1 ----
  float2 xi[4];
#pragma unroll
  for (int r = 0; r < 4; ++r)
    xi[r] = *(const float2*)(x + (size_t)(i0 + r) * Dn + 2 * c2);

  float2 acc[4];
#pragma unroll
  for (int r = 0; r < 4; ++r) acc[r] = make_float2(0.f, 0.f);

  const float4* gx = (const float4*)x;     // tile k = float4 [k*2048, +2048)
  const int fa = wave * 128 + lane;        // this thread's 2 slots: fa, fa+64

  // prime: tile 0 -> bufA (synchronous), then issue tile-1 loads.
  {
    const float4 p0 = gx[fa];
    const float4 p1 = gx[fa + 64];
    *(float4*)&bufA[fa * 4] = p0;
    *(float4*)&bufA[fa * 4 + 256] = p1;
  }
  float4 n0 = gx[2048 + fa];
  float4 n1 = gx[2048 + fa + 64];
  __syncthreads();  // bufA staged (one exposed drain of tile-1 loads; only here)

#pragma unroll 1
  for (int k = 0; k < 16; ++k) {
    if (k < 15) {  // write tile k+1 (regs, loads long since drained) -> spare buf
      float* nb = ((k + 1) & 1) ? bufB : bufA;
      *(float4*)&nb[fa * 4] = n0;
      *(float4*)&nb[fa * 4 + 256] = n1;
    }
    if (k < 14) {  // issue tile k+2 loads; drained at THIS iter's barrier,
                   // with the whole compute-k between issue and drain
      n0 = gx[(size_t)(k + 2) * 2048 + fa];
      n1 = gx[(size_t)(k + 2) * 2048 + fa + 64];
    }
    const float* tb = (k & 1) ? bufB : bufA;
#pragma unroll
    for (int u = 0; u < 4; ++u) {
      const float2 xj = *(const float2*)&tb[(wave * 4 + u) * Dn + 2 * c2];
#pragma unroll
      for (int r = 0; r < 4; ++r) {
        acc[r].x += fabsf(xi[r].x - xj.x);
        acc[r].y += fabsf(xi[r].y - xj.y);
      }
    }
    __syncthreads();  // tile k+1 buffer staged; compute-k readers done
  }

#pragma unroll
  for (int r = 0; r < 4; ++r) *(float2*)&red[wave][r][2 * c2] = acc[r];
  __syncthreads();

  // ---- Phase 2: reduce 16 wave-partials; stage xs, wt_s ----
  if (t < 512) {
    const int r = t >> 7, d = t & 127;
    float s = 0.f;
#pragma unroll
    for (int qq = 0; qq < 16; ++qq) s += red[qq][r][d];
    dms[r][d] = s * (1.0f / 1024.0f);
    xs[r][d] = x[(size_t)(i0 + r) * Dn + d];
  } else if (t < 640) {
    wt_s[t - 512] = Wt[t - 512];
  }
  __syncthreads();

  // ---- Phase 3: tau (one wave per row, t<256) ----
  if (t < 256) {
    const int r = t >> 6, p = t & 63;
    float partial = xs[r][p] * wt_s[p] + xs[r][p + 64] * wt_s[p + 64];
#pragma unroll
    for (int off = 32; off; off >>= 1) partial += __shfl_xor(partial, off, 64);
    if (p == 0) {
      const float z = partial + bt[0];
      const float sp = fmaxf(z, 0.f) + log1pf(expf(-fabsf(z)));  // softplus
      tau_s[r] = 1.0f / (fmaxf(sp, 0.01f) + 1.0f);
    }
  }
  __syncthreads();

  // ---- Phase 4a: m = (Wd . dm + bd) / tau (t<256) ----
  if (t < 256) {
    const int h = t & 127;
    const int g4 = t >> 7;
    const int r0 = 2 * g4, r1 = 2 * g4 + 1;
    float m0 = bd[h], m1 = m0;
    const float4* w = (const float4*)(Wd + (size_t)h * Dn);
#pragma unroll 4
    for (int k4 = 0; k4 < Dn / 4; ++k4) {
      const float4 wv = w[k4];
      const int k = k4 * 4;
      m0 += wv.x * dms[r0][k] + wv.y * dms[r0][k + 1] +
            wv.z * dms[r0][k + 2] + wv.w * dms[r0][k + 3];
      m1 += wv.x * dms[r1][k] + wv.y * dms[r1][k + 1] +
            wv.z * dms[r1][k + 2] + wv.w * dms[r1][k + 3];
    }
    ms[r0][h] = m0 * tau_s[r0];
    ms[r1][h] = m1 * tau_s[r1];
  }
  __syncthreads();

  // ---- Phase 4b: y = relu(Wa . m + ba) + Wr . x + br (t<256) ----
  if (t < 256) {
    const int h = t & 127;
    const int g4 = t >> 7;
    const int r0 = 2 * g4, r1 = 2 * g4 + 1;
    float q0 = ba[h], q1 = q0, c0 = br[h], c1 = c0;
    const float4* wa = (const float4*)(Wa + (size_t)h * Dn);
    const float4* wr = (const float4*)(Wr + (size_t)h * Dn);
#pragma unroll 4
    for (int k4 = 0; k4 < Dn / 4; ++k4) {
      const float4 av = wa[k4];
      const float4 rv = wr[k4];
      const int k = k4 * 4;
      q0 += av.x * ms[r0][k] + av.y * ms[r0][k + 1] +
            av.z * ms[r0][k + 2] + av.w * ms[r0][k + 3];
      q1 += av.x * ms[r1][k] + av.y * ms[r1][k + 1] +
            av.z * ms[r1][k + 2] + av.w * ms[r1][k + 3];
      c0 += rv.x * xs[r0][k] + rv.y * xs[r0][k + 1] +
            rv.z * xs[r0][k + 2] + rv.w * xs[r0][k + 3];
      c1 += rv.x * xs[r1][k] + rv.y * xs[r1][k + 1] +
            rv.z * xs[r1][k + 2] + rv.w * xs[r1][k + 3];
    }
    ys[r0][h] = fmaxf(q0, 0.f) + c0;
    ys[r1][h] = fmaxf(q1, 0.f) + c1;
  }
  __syncthreads();

  // ---- Phase 5: LayerNorm (one wave per row, t<256) ----
  if (t < 256) {
    const int r = t >> 6, p = t & 63;
    const float v0 = ys[r][p], v1 = ys[r][p + 64];
    float s = v0 + v1;
    float qq = v0 * v0 + v1 * v1;
#pragma unroll
    for (int off = 32; off; off >>= 1) {
      s += __shfl_xor(s, off, 64);
      qq += __shfl_xor(qq, off, 64);
    }
    const float mu = s * (1.0f / 128.0f);
    const float var = qq * (1.0f / 128.0f) - mu * mu;
    const float rs = rsqrtf(var + 1e-5f);
    float* o = out + (size_t)(i0 + r) * Hn;
    o[p]      = (v0 - mu) * rs * gamma[p]      + beta[p];
    o[p + 64] = (v1 - mu) * rs * gamma[p + 64] + beta[p + 64];
  }
}

extern "C" void kernel_launch(void* const* d_in, const int* in_sizes, int n_in,
                              void* d_out, int out_size, void* d_ws, size_t ws_size,
                              hipStream_t stream) {
  const float* x     = (const float*)d_in[0];
  const float* Wd    = (const float*)d_in[1];
  const float* bd    = (const float*)d_in[2];
  const float* Wt    = (const float*)d_in[3];
  const float* bt    = (const float*)d_in[4];
  const float* Wa    = (const float*)d_in[5];
  const float* ba    = (const float*)d_in[6];
  const float* Wr    = (const float*)d_in[7];
  const float* br    = (const float*)d_in[8];
  const float* gamma = (const float*)d_in[9];
  const float* beta  = (const float*)d_in[10];
  float* out = (float*)d_out;

  fused_resd1<<<Bn / 4, 1024, 0, stream>>>(x, Wd, bd, Wt, bt, Wa, ba, Wr, br,
                                           gamma, beta, out);
  (void)in_sizes; (void)n_in; (void)out_size; (void)d_ws; (void)ws_size;
}